// Round 20
// baseline (174.601 us; speedup 1.0000x reference)
//
#include <hip/hip_runtime.h>
#include <math.h>

#define DIMX 1024
#define D_STATE 16
#define D_INNER 2048
#define DT_RANK 64
#define B_SZ 2
#define L_SEQ 1024
#define NTOK (B_SZ * L_SEQ)
#define EPSR 1e-5f
#define NC 32          // chunks per sequence
#define LC 32          // steps per chunk
#define NCH (B_SZ * D_INNER)            // 4096 channels
#define NLANE (NCH * D_STATE)           // 65536 (chan,state) pairs
#define LOG2E 1.44269504f

typedef __attribute__((ext_vector_type(8))) short bf16x8;
typedef __attribute__((ext_vector_type(4))) int   i32x4;
typedef __attribute__((ext_vector_type(4))) float f32x4;
typedef __attribute__((ext_vector_type(4))) unsigned short u16x4;

__device__ __forceinline__ unsigned short f2b(float f) {
    unsigned int u = __builtin_bit_cast(unsigned int, f);
    u += 0x7fffu + ((u >> 16) & 1u);          // RNE
    return (unsigned short)(u >> 16);
}
__device__ __forceinline__ float b2f(unsigned short h) {
    unsigned int u = ((unsigned int)h) << 16;
    return __builtin_bit_cast(float, u);
}
__device__ __forceinline__ float lo2f(unsigned int v) {       // low bf16 -> f32
    return __builtin_bit_cast(float, v << 16);
}
__device__ __forceinline__ float hi2f(unsigned int v) {       // high bf16 -> f32
    return __builtin_bit_cast(float, v & 0xffff0000u);
}
// async global->LDS, 16B per lane, wave-uniform LDS base + lane*16
__device__ __forceinline__ void gload16(const void* g, void* l) {
    __builtin_amdgcn_global_load_lds(
        (const __attribute__((address_space(1))) unsigned int*)g,
        (__attribute__((address_space(3))) unsigned int*)l, 16, 0, 0);
}

// ---------------- fused prep: all weight f32->bf16 conversions + RMSNorm ----------------
#define N1C (2 * D_INNER * DIMX / 4)
#define N2C (96 * D_INNER / 4)
#define N3C (D_INNER * DT_RANK / 4)
#define N4C (DIMX * D_INNER / 4)
#define NWCONV ((N1C + N2C + N3C + N4C + 255) / 256)
__global__ __launch_bounds__(256) void prep_kernel(
    const float* __restrict__ w_in, const float* __restrict__ w_x,
    const float* __restrict__ w_dt, const float* __restrict__ w_out,
    const float* __restrict__ x, const float* __restrict__ norm_w,
    unsigned short* __restrict__ o_in, unsigned short* __restrict__ o_x,
    unsigned short* __restrict__ o_dt, unsigned short* __restrict__ o_out,
    unsigned short* __restrict__ xnb) {
    if ((int)blockIdx.x < NWCONV) {
        int i = blockIdx.x * 256 + threadIdx.x;
        const float* src; unsigned short* dst; int j;
        if (i < N1C)                        { src = w_in;  dst = o_in;  j = i; }
        else if (i < N1C + N2C)             { src = w_x;   dst = o_x;   j = i - N1C; }
        else if (i < N1C + N2C + N3C)       { src = w_dt;  dst = o_dt;  j = i - N1C - N2C; }
        else if (i < N1C + N2C + N3C + N4C) { src = w_out; dst = o_out; j = i - N1C - N2C - N3C; }
        else return;
        f32x4 v = *(const f32x4*)(src + (size_t)j * 4);
        unsigned short o[4];
#pragma unroll
        for (int k = 0; k < 4; ++k) o[k] = f2b(v[k]);
        *(unsigned long long*)(dst + (size_t)j * 4) = *(unsigned long long*)o;
    } else {
        int row = blockIdx.x - NWCONV;
        const float* xr = x + (size_t)row * DIMX;
        unsigned short* outr = xnb + (size_t)row * DIMX;
        int t = threadIdx.x;
        float v[4];
        float ss = 0.f;
#pragma unroll
        for (int i = 0; i < 4; ++i) { v[i] = xr[t + i * 256]; ss += v[i] * v[i]; }
#pragma unroll
        for (int off = 32; off > 0; off >>= 1) ss += __shfl_down(ss, off);
        __shared__ float red[4];
        if ((t & 63) == 0) red[t >> 6] = ss;
        __syncthreads();
        float tot = red[0] + red[1] + red[2] + red[3];
        float scale = rsqrtf(tot * (1.f / DIMX) + EPSR);
#pragma unroll
        for (int i = 0; i < 4; ++i) outr[t + i * 256] = f2b(v[i] * scale * norm_w[t + i * 256]);
    }
}

// ---------------- FUSED depthwise causal conv + SiLU, row-major in/out [t][d] ----------------
__global__ __launch_bounds__(256) void conv_silu_row(
    const unsigned short* __restrict__ xiR, const float* __restrict__ cw,
    const float* __restrict__ cb, unsigned short* __restrict__ u_row) {
    __shared__ unsigned int xs[67 * 65];       // [t_local 0..66][d 0..63], t = t0-3+row
    __shared__ unsigned int ob[64 * 65];
    const int t0 = blockIdx.x * 64;
    const int d0 = blockIdx.y * 64;
    const int bstart = t0 & ~(L_SEQ - 1);
    const int tid = threadIdx.x;
    for (int task = tid; task < 536; task += 256) {   // 67 rows x 8 chunks of 8 channels
        int row = task >> 3, c8 = (task & 7) * 8;
        int t = t0 - 3 + row;
        if (t >= bstart) {
            i32x4 v = *(const i32x4*)(xiR + (size_t)t * D_INNER + d0 + c8);
            const unsigned short* vs = (const unsigned short*)&v;
#pragma unroll
            for (int i = 0; i < 8; ++i)
                xs[row * 65 + c8 + i] = __builtin_bit_cast(unsigned int, b2f(vs[i]));
        } else {
#pragma unroll
            for (int i = 0; i < 8; ++i) xs[row * 65 + c8 + i] = 0u;
        }
    }
    __syncthreads();
    {
        const int dl = tid & 63, tr = tid >> 6;
        const int d = d0 + dl, lt0 = tr * 16;
        const float w0 = cw[d * 4 + 0], w1 = cw[d * 4 + 1], w2 = cw[d * 4 + 2], w3 = cw[d * 4 + 3];
        const float bias = cb[d];
        float x0 = __builtin_bit_cast(float, xs[(lt0 + 0) * 65 + dl]);
        float x1 = __builtin_bit_cast(float, xs[(lt0 + 1) * 65 + dl]);
        float x2 = __builtin_bit_cast(float, xs[(lt0 + 2) * 65 + dl]);
#pragma unroll
        for (int i = 0; i < 16; ++i) {
            float x3 = __builtin_bit_cast(float, xs[(lt0 + 3 + i) * 65 + dl]);
            float a = bias + w0 * x0 + w1 * x1 + w2 * x2 + w3 * x3;
            ob[(lt0 + i) * 65 + dl] = f2b(a / (1.f + __expf(-a)));
            x0 = x1; x1 = x2; x2 = x3;
        }
    }
    __syncthreads();
#pragma unroll
    for (int it = 0; it < 2; ++it) {
        int k = tid + it * 256;
        int t = k >> 3, d8 = (k & 7) * 8;
        unsigned short o[8];
#pragma unroll
        for (int j = 0; j < 8; ++j) o[j] = (unsigned short)ob[t * 65 + d8 + j];
        *(i32x4*)(u_row + (size_t)(t0 + t) * D_INNER + d0 + d8) = *(const i32x4*)o;
    }
}

// ---------------- bf16 MFMA GEMM with global_load_lds staging ----------------
// EPI 0: row-major f32 partial store (split-K via blockIdx.z plane offset)
// EPI 1: dt_proj: delta=softplus(acc+bias[col]); ddu[t][d]=pack(delta,delta*u); uD[t][d]=u*D
// EPI 3: in_proj: col<2048 -> xi_row [t][d]; col>=2048 -> z_row [t][d]  (both coalesced)
template <int EPI>
__global__ __launch_bounds__(256) void gemm_mfma(
    const unsigned short* __restrict__ A, const unsigned short* __restrict__ B,
    void* __restrict__ C, void* __restrict__ C2,
    int M, int N, int K, int lda, int ldb, int ldc,
    const float* __restrict__ bias, const float* __restrict__ res,
    const float* __restrict__ aux) {
    __shared__ unsigned short As[128 * 32];
    __shared__ unsigned short Bs[128 * 32];
    const int tid = threadIdx.x;
    const int m0 = blockIdx.y * 128, n0 = blockIdx.x * 128;
    const int lane = tid & 63, wave = tid >> 6;
    const int wr = (wave >> 1) * 64, wc = (wave & 1) * 64;
    const int fr = lane & 15, fk = (lane >> 4) * 8;
    const int kspan = K / gridDim.z;
    const int kb = blockIdx.z * kspan;
    const int srow = lane >> 2, sc8 = (lane & 3) * 8;
    f32x4 acc[4][4] = {};
    for (int k0 = kb; k0 < kb + kspan; k0 += 32) {
#pragma unroll
        for (int i = 0; i < 2; ++i) {
            int q = wave + 4 * i;
            int row = q * 16 + srow;
            gload16(A + (size_t)(m0 + row) * lda + k0 + sc8, (unsigned short*)As + q * 512);
            gload16(B + (size_t)(n0 + row) * ldb + k0 + sc8, (unsigned short*)Bs + q * 512);
        }
        __syncthreads();
        bf16x8 af[4], bfr[4];
#pragma unroll
        for (int i = 0; i < 4; ++i) af[i]  = *(const bf16x8*)&As[(wr + i * 16 + fr) * 32 + fk];
#pragma unroll
        for (int j = 0; j < 4; ++j) bfr[j] = *(const bf16x8*)&Bs[(wc + j * 16 + fr) * 32 + fk];
#pragma unroll
        for (int i = 0; i < 4; ++i)
#pragma unroll
            for (int j = 0; j < 4; ++j)
                acc[i][j] = __builtin_amdgcn_mfma_f32_16x16x32_bf16(af[i], bfr[j], acc[i][j], 0, 0, 0);
        __syncthreads();
    }
    const int er = (lane >> 4) * 4;
    if (EPI == 3) {
        unsigned short* xiR = (unsigned short*)C;
        unsigned short* zR  = (unsigned short*)C2;
#pragma unroll
        for (int i = 0; i < 4; ++i)
#pragma unroll
            for (int j = 0; j < 4; ++j) {
                int row0 = m0 + wr + i * 16 + er;
                int col = n0 + wc + j * 16 + fr;
                unsigned short* dst;
                int colm;
                if (col < D_INNER) { dst = xiR; colm = col; }
                else               { dst = zR;  colm = col - D_INNER; }
#pragma unroll
                for (int r = 0; r < 4; ++r)
                    dst[(size_t)(row0 + r) * D_INNER + colm] = f2b(acc[i][j][r]);
            }
    } else if (EPI == 1) {
        const unsigned short* uR = (const unsigned short*)res;   // u_row bf16 [t][d]
        unsigned int* dduP = (unsigned int*)C;
        unsigned short* uDP = (unsigned short*)C2;
#pragma unroll
        for (int i = 0; i < 4; ++i)
#pragma unroll
            for (int j = 0; j < 4; ++j) {
                int row0 = m0 + wr + i * 16 + er;
                int col = n0 + wc + j * 16 + fr;
                float bb = bias[col];
                float Dv = aux[col];
#pragma unroll
                for (int r = 0; r < 4; ++r) {
                    size_t idx = (size_t)(row0 + r) * D_INNER + col;
                    float t = acc[i][j][r] + bb;
                    float v = fmaxf(t, 0.f) + __logf(1.f + __expf(-fabsf(t)));   // fast softplus
                    float uf = b2f(uR[idx]);
                    dduP[idx] = ((unsigned)f2b(v)) | (((unsigned)f2b(v * uf)) << 16);
                    uDP[idx] = f2b(uf * Dv);
                }
            }
    } else {
        float* Cs = (float*)C + (size_t)blockIdx.z * M * ldc;
#pragma unroll
        for (int i = 0; i < 4; ++i)
#pragma unroll
            for (int j = 0; j < 4; ++j) {
                int col = n0 + wc + j * 16 + fr;
                if (col < N) {
#pragma unroll
                    for (int r = 0; r < 4; ++r) {
                        int row = m0 + wr + i * 16 + er + r;
                        Cs[(size_t)row * ldc + col] = acc[i][j][r];
                    }
                }
            }
    }
}

// ---------------- out_proj split-K=2 combine + residual ----------------
__global__ void combine_residual(const float* __restrict__ part, const float* __restrict__ x,
                                 float* __restrict__ out) {
    int i = blockIdx.x * 256 + threadIdx.x;
    f32x4 s = *(const f32x4*)(x + (size_t)i * 4);
#pragma unroll
    for (int z = 0; z < 2; ++z)
        s += *(const f32x4*)(part + (size_t)z * NTOK * DIMX + (size_t)i * 4);
    *(f32x4*)(out + (size_t)i * 4) = s;
}

// ---------------- x_proj split-K combine ----------------
__global__ void xproj_combine(const float* __restrict__ xp, unsigned short* __restrict__ xdbl_b,
                              float* __restrict__ B_T, float* __restrict__ C_T) {
    int row = blockIdx.x;
    int col = threadIdx.x;
    if (col >= 96) return;
    float s = 0.f;
#pragma unroll
    for (int p = 0; p < 8; ++p) s += xp[(size_t)p * NTOK * 96 + (size_t)row * 96 + col];
    if (col < 64) xdbl_b[row * 64 + col] = f2b(s);
    else if (col < 80) B_T[(size_t)(col - 64) * NTOK + row] = s;
    else C_T[(size_t)(col - 80) * NTOK + row] = s;
}

// ================= Chunked selective scan: lane = channel, states in registers =================

__global__ __launch_bounds__(256) void scan_pass1(
    const unsigned int* __restrict__ ddu, const float* __restrict__ B_T,
    const float* __restrict__ A_log, float* __restrict__ hl, float* __restrict__ Pc) {
    __shared__ float bs[LC][20];
    const int tid = threadIdx.x;
    const int chunk = blockIdx.x;
    const int gchan = blockIdx.y * 256 + tid;
    const int b = gchan >> 11, d = gchan & (D_INNER - 1);
    const int tb = b * L_SEQ + chunk * LC;
    for (int v = tid; v < LC * 16; v += 256) {
        int t = v & (LC - 1), s = v >> 5;
        bs[t][s] = B_T[(size_t)s * NTOK + tb + t];
    }
    __syncthreads();
    float A2[D_STATE], h[D_STATE];
    const float* al = A_log + d * D_STATE;
#pragma unroll
    for (int s = 0; s < D_STATE; ++s) { A2[s] = -__expf(al[s]) * LOG2E; h[s] = 0.f; }
    float dsum = 0.f;
    const unsigned int* pd = ddu + (size_t)tb * D_INNER + d;
    unsigned int pf[8];
#pragma unroll
    for (int t = 0; t < 8; ++t) pf[t] = pd[(size_t)t * D_INNER];
#pragma unroll
    for (int t = 0; t < LC; ++t) {
        unsigned int v = pf[t & 7];
        if (t + 8 < LC) pf[t & 7] = pd[(size_t)(t + 8) * D_INNER];
        float dl = lo2f(v), du = hi2f(v);
        dsum += dl;
#pragma unroll
        for (int i = 0; i < 4; ++i) {
            f32x4 bv = *(const f32x4*)&bs[t][4 * i];
#pragma unroll
            for (int q = 0; q < 4; ++q) {
                int s = 4 * i + q;
                float e = exp2f(dl * A2[s]);
                h[s] = e * h[s] + du * bv[q];
            }
        }
    }
    float* ph = hl + (size_t)chunk * NLANE + (size_t)gchan * D_STATE;
    float* pp = Pc + (size_t)chunk * NLANE + (size_t)gchan * D_STATE;
#pragma unroll
    for (int q = 0; q < 4; ++q) {
        f32x4 hv = {h[4 * q], h[4 * q + 1], h[4 * q + 2], h[4 * q + 3]};
        f32x4 pv = {exp2f(dsum * A2[4 * q]),     exp2f(dsum * A2[4 * q + 1]),
                    exp2f(dsum * A2[4 * q + 2]), exp2f(dsum * A2[4 * q + 3])};
        *(f32x4*)(ph + 4 * q) = hv;
        *(f32x4*)(pp + 4 * q) = pv;
    }
}

__global__ __launch_bounds__(256) void scan_pass2(const float* __restrict__ hl,
                                                  const float* __restrict__ Pc,
                                                  float* __restrict__ hi) {
    int gid = blockIdx.x * 256 + threadIdx.x;
    float h = 0.f;
    hi[gid] = 0.f;
#pragma unroll
    for (int c = 1; c < NC; ++c) {
        h = hl[(size_t)(c - 1) * NLANE + gid] + Pc[(size_t)(c - 1) * NLANE + gid] * h;
        hi[(size_t)c * NLANE + gid] = h;
    }
}

__global__ __launch_bounds__(256) void scan_pass3(
    const unsigned int* __restrict__ ddu, const float* __restrict__ B_T,
    const float* __restrict__ C_T, const unsigned short* __restrict__ uD,
    const unsigned short* __restrict__ z_row, const float* __restrict__ A_log,
    const float* __restrict__ hi, unsigned short* __restrict__ y_row) {
    __shared__ float bcs[LC][36];
    const int tid = threadIdx.x;
    const int chunk = blockIdx.x;
    const int gchan = blockIdx.y * 256 + tid;
    const int b = gchan >> 11, d = gchan & (D_INNER - 1);
    const int tb = b * L_SEQ + chunk * LC;
    for (int v = tid; v < LC * 32; v += 256) {
        int t = v & (LC - 1), q = v >> 5;
        bcs[t][q] = (q < 16) ? B_T[(size_t)q * NTOK + tb + t]
                             : C_T[(size_t)(q - 16) * NTOK + tb + t];
    }
    __syncthreads();
    float A2[D_STATE], h[D_STATE];
    const float* al = A_log + d * D_STATE;
#pragma unroll
    for (int s = 0; s < D_STATE; ++s) A2[s] = -__expf(al[s]) * LOG2E;
    const float* ph = hi + (size_t)chunk * NLANE + (size_t)gchan * D_STATE;
#pragma unroll
    for (int q = 0; q < 4; ++q) {
        f32x4 hv = *(const f32x4*)(ph + 4 * q);
#pragma unroll
        for (int r = 0; r < 4; ++r) h[4 * q + r] = hv[r];
    }
    const unsigned int* pd = ddu + (size_t)tb * D_INNER + d;
    const unsigned short* pu = uD + (size_t)tb * D_INNER + d;
    const unsigned short* pz = z_row + (size_t)tb * D_INNER + d;
    unsigned short* py = y_row + (size_t)tb * D_INNER + d;
    unsigned int pf[4];
    unsigned short pfu[4], pfz[4];
#pragma unroll
    for (int t = 0; t < 4; ++t) {
        pf[t] = pd[(size_t)t * D_INNER];
        pfu[t] = pu[(size_t)t * D_INNER];
        pfz[t] = pz[(size_t)t * D_INNER];
    }
#pragma unroll
    for (int t = 0; t < LC; ++t) {
        unsigned int v = pf[t & 3];
        float uDv = b2f(pfu[t & 3]);
        float zz = b2f(pfz[t & 3]);
        if (t + 4 < LC) {
            pf[t & 3] = pd[(size_t)(t + 4) * D_INNER];
            pfu[t & 3] = pu[(size_t)(t + 4) * D_INNER];
            pfz[t & 3] = pz[(size_t)(t + 4) * D_INNER];
        }
        float dl = lo2f(v), du = hi2f(v);
        float y0 = 0.f, y1 = 0.f, y2 = 0.f, y3 = 0.f;
#pragma unroll
        for (int i = 0; i < 4; ++i) {
            f32x4 bv = *(const f32x4*)&bcs[t][4 * i];
            f32x4 cv = *(const f32x4*)&bcs[t][16 + 4 * i];
#pragma unroll
            for (int q = 0; q < 4; ++q) {
                int s = 4 * i + q;
                float e = exp2f(dl * A2[s]);
                h[s] = e * h[s] + du * bv[q];
                float yv = h[s] * cv[q];
                if (q == 0) y0 += yv;
                else if (q == 1) y1 += yv;
                else if (q == 2) y2 += yv;
                else y3 += yv;
            }
        }
        float y = (y0 + y1) + (y2 + y3);
        float yy = y + uDv;
        py[(size_t)t * D_INNER] = f2b(yy * (zz / (1.f + __expf(-zz))));
    }
}

extern "C" void kernel_launch(void* const* d_in, const int* in_sizes, int n_in,
                              void* d_out, int out_size, void* d_ws, size_t ws_size,
                              hipStream_t stream) {
    const float* x          = (const float*)d_in[0];
    const float* norm_w     = (const float*)d_in[1];
    const float* in_proj_w  = (const float*)d_in[2];
    const float* conv_w     = (const float*)d_in[3];
    const float* conv_b     = (const float*)d_in[4];
    const float* x_proj_w   = (const float*)d_in[5];
    const float* dt_proj_w  = (const float*)d_in[6];
    const float* dt_proj_b  = (const float*)d_in[7];
    const float* A_log      = (const float*)d_in[8];
    const float* D_param    = (const float*)d_in[9];
    const float* out_proj_w = (const float*)d_in[10];
    float* out = (float*)d_out;

    char* p = (char*)d_ws;
    unsigned short* xi_row = (unsigned short*)p; p += (size_t)NTOK * D_INNER * 2;  // 8.39 MB
    unsigned short* z_row  = (unsigned short*)p; p += (size_t)NTOK * D_INNER * 2;  // 8.39 MB
    unsigned int*   ddu    = (unsigned int*)p;   p += (size_t)NTOK * D_INNER * 4;  // 16.78 MB
    unsigned short* u_row  = (unsigned short*)p; p += (size_t)NTOK * D_INNER * 2;  // 8.39 MB
    unsigned short* uD     = (unsigned short*)p; p += (size_t)NTOK * D_INNER * 2;  // 8.39 MB
    unsigned short* y_row  = (unsigned short*)p; p += (size_t)NTOK * D_INNER * 2;  // 8.39 MB
    unsigned short* xdbl_b = (unsigned short*)p; p += (size_t)NTOK * 64 * 2;       // 0.26 MB
    float* B_T = (float*)p;  p += (size_t)D_STATE * NTOK * 4;                      // 0.13 MB
    float* C_T = (float*)p;  p += (size_t)D_STATE * NTOK * 4;                      // 0.13 MB
    unsigned short* xn_b = (unsigned short*)p; p += (size_t)NTOK * DIMX * 2;       // 4.19 MB
    unsigned short* w_in_b  = (unsigned short*)p; p += (size_t)2 * D_INNER * DIMX * 2;  // 8.39 MB
    unsigned short* w_x_b   = (unsigned short*)p; p += (size_t)96 * D_INNER * 2;
    unsigned short* w_dt_b  = (unsigned short*)p; p += (size_t)D_INNER * DT_RANK * 2;
    unsigned short* w_out_b = (unsigned short*)p; p += (size_t)DIMX * D_INNER * 2;

    // overlays (disjoint lifetimes):
    float* xp_part = (float*)y_row;            // 6.29 MB (y_row written only by pass3)
    float* hl = (float*)u_row;                 // 8.39 MB (u_row dead after dt_proj; pass1+)
    float* Pc = (float*)w_in_b;                // 8.39 MB (w_in dead after in_proj; pass1+)
    float* hi = (float*)xi_row;                // 8.39 MB (xi_row dead after conv; pass2+)
    float* out_part = (float*)ddu;             // 16.78 MB (split-K=2; ddu dead after pass3)

    // 0. fused prep: weight conversions + RMSNorm
    prep_kernel<<<NWCONV + NTOK, 256, 0, stream>>>(
        in_proj_w, x_proj_w, dt_proj_w, out_proj_w, x, norm_w,
        w_in_b, w_x_b, w_dt_b, w_out_b, xn_b);
    // 1. in_proj: xi_row [t][d] + z_row [t][d]
    gemm_mfma<3><<<dim3(32, 16), 256, 0, stream>>>(xn_b, w_in_b, xi_row, z_row,
        NTOK, 2 * D_INNER, DIMX, DIMX, DIMX, D_INNER, nullptr, nullptr, nullptr);
    // 2. FUSED conv + SiLU -> u_row [t][d]
    conv_silu_row<<<dim3(NTOK / 64, D_INNER / 64), 256, 0, stream>>>(
        xi_row, conv_w, conv_b, u_row);
    // 3. x_proj split-K=8 partials + combine
    gemm_mfma<0><<<dim3(1, 16, 8), 256, 0, stream>>>(u_row, w_x_b, xp_part, nullptr,
        NTOK, 96, D_INNER, D_INNER, D_INNER, 96, nullptr, nullptr, nullptr);
    xproj_combine<<<NTOK, 128, 0, stream>>>(xp_part, xdbl_b, B_T, C_T);
    // 4. dt_proj: ddu [t][d] (packed bf16 delta,du) + uD [t][d] (u*D)
    gemm_mfma<1><<<dim3(16, 16), 256, 0, stream>>>(xdbl_b, w_dt_b, ddu, uD,
        NTOK, D_INNER, DT_RANK, 64, DT_RANK, D_INNER, dt_proj_b, (const float*)u_row, D_param);
    // 5. chunked selective scan (lane=channel, states in registers)
    scan_pass1<<<dim3(NC, NCH / 256), 256, 0, stream>>>(ddu, B_T, A_log, hl, Pc);
    scan_pass2<<<NLANE / 256, 256, 0, stream>>>(hl, Pc, hi);
    scan_pass3<<<dim3(NC, NCH / 256), 256, 0, stream>>>(ddu, B_T, C_T, uD, z_row, A_log, hi, y_row);
    // 6. out_proj split-K=2 -> partials (ddu region dead after pass3)
    gemm_mfma<0><<<dim3(8, 16, 2), 256, 0, stream>>>(y_row, w_out_b, out_part, nullptr,
        NTOK, DIMX, D_INNER, D_INNER, D_INNER, DIMX, nullptr, nullptr, nullptr);
    // 7. combine partials + residual -> out
    combine_residual<<<NTOK * DIMX / 4 / 256, 256, 0, stream>>>(out_part, x, out);
}

// Round 21
// 170.002 us; speedup vs baseline: 1.0271x; 1.0271x over previous
//
#include <hip/hip_runtime.h>
#include <math.h>

#define DIMX 1024
#define D_STATE 16
#define D_INNER 2048
#define DT_RANK 64
#define B_SZ 2
#define L_SEQ 1024
#define NTOK (B_SZ * L_SEQ)
#define EPSR 1e-5f
#define NC 32          // chunks per sequence
#define LC 32          // steps per chunk
#define NCH (B_SZ * D_INNER)            // 4096 channels
#define NLANE (NCH * D_STATE)           // 65536 (chan,state) pairs
#define LOG2E 1.44269504f

typedef __attribute__((ext_vector_type(8))) short bf16x8;
typedef __attribute__((ext_vector_type(4))) int   i32x4;
typedef __attribute__((ext_vector_type(4))) float f32x4;
typedef __attribute__((ext_vector_type(4))) unsigned short u16x4;

__device__ __forceinline__ unsigned short f2b(float f) {
    unsigned int u = __builtin_bit_cast(unsigned int, f);
    u += 0x7fffu + ((u >> 16) & 1u);          // RNE
    return (unsigned short)(u >> 16);
}
__device__ __forceinline__ float b2f(unsigned short h) {
    unsigned int u = ((unsigned int)h) << 16;
    return __builtin_bit_cast(float, u);
}
__device__ __forceinline__ float lo2f(unsigned int v) {       // low bf16 -> f32
    return __builtin_bit_cast(float, v << 16);
}
__device__ __forceinline__ float hi2f(unsigned int v) {       // high bf16 -> f32
    return __builtin_bit_cast(float, v & 0xffff0000u);
}
// async global->LDS, 16B per lane, wave-uniform LDS base + lane*16
__device__ __forceinline__ void gload16(const void* g, void* l) {
    __builtin_amdgcn_global_load_lds(
        (const __attribute__((address_space(1))) unsigned int*)g,
        (__attribute__((address_space(3))) unsigned int*)l, 16, 0, 0);
}

// ---------------- fused prep: all weight f32->bf16 conversions + RMSNorm ----------------
#define N1C (2 * D_INNER * DIMX / 4)
#define N2C (96 * D_INNER / 4)
#define N3C (D_INNER * DT_RANK / 4)
#define N4C (DIMX * D_INNER / 4)
#define NWCONV ((N1C + N2C + N3C + N4C + 255) / 256)
__global__ __launch_bounds__(256) void prep_kernel(
    const float* __restrict__ w_in, const float* __restrict__ w_x,
    const float* __restrict__ w_dt, const float* __restrict__ w_out,
    const float* __restrict__ x, const float* __restrict__ norm_w,
    unsigned short* __restrict__ o_in, unsigned short* __restrict__ o_x,
    unsigned short* __restrict__ o_dt, unsigned short* __restrict__ o_out,
    unsigned short* __restrict__ xnb) {
    if ((int)blockIdx.x < NWCONV) {
        int i = blockIdx.x * 256 + threadIdx.x;
        const float* src; unsigned short* dst; int j;
        if (i < N1C)                        { src = w_in;  dst = o_in;  j = i; }
        else if (i < N1C + N2C)             { src = w_x;   dst = o_x;   j = i - N1C; }
        else if (i < N1C + N2C + N3C)       { src = w_dt;  dst = o_dt;  j = i - N1C - N2C; }
        else if (i < N1C + N2C + N3C + N4C) { src = w_out; dst = o_out; j = i - N1C - N2C - N3C; }
        else return;
        f32x4 v = *(const f32x4*)(src + (size_t)j * 4);
        unsigned short o[4];
#pragma unroll
        for (int k = 0; k < 4; ++k) o[k] = f2b(v[k]);
        *(unsigned long long*)(dst + (size_t)j * 4) = *(unsigned long long*)o;
    } else {
        int row = blockIdx.x - NWCONV;
        const float* xr = x + (size_t)row * DIMX;
        unsigned short* outr = xnb + (size_t)row * DIMX;
        int t = threadIdx.x;
        float v[4];
        float ss = 0.f;
#pragma unroll
        for (int i = 0; i < 4; ++i) { v[i] = xr[t + i * 256]; ss += v[i] * v[i]; }
#pragma unroll
        for (int off = 32; off > 0; off >>= 1) ss += __shfl_down(ss, off);
        __shared__ float red[4];
        if ((t & 63) == 0) red[t >> 6] = ss;
        __syncthreads();
        float tot = red[0] + red[1] + red[2] + red[3];
        float scale = rsqrtf(tot * (1.f / DIMX) + EPSR);
#pragma unroll
        for (int i = 0; i < 4; ++i) outr[t + i * 256] = f2b(v[i] * scale * norm_w[t + i * 256]);
    }
}

// ---------------- FUSED depthwise causal conv + SiLU, row-major in/out [t][d] ----------------
__global__ __launch_bounds__(256) void conv_silu_row(
    const unsigned short* __restrict__ xiR, const float* __restrict__ cw,
    const float* __restrict__ cb, unsigned short* __restrict__ u_row) {
    __shared__ unsigned int xs[67 * 65];       // [t_local 0..66][d 0..63], t = t0-3+row
    __shared__ unsigned int ob[64 * 65];
    const int t0 = blockIdx.x * 64;
    const int d0 = blockIdx.y * 64;
    const int bstart = t0 & ~(L_SEQ - 1);
    const int tid = threadIdx.x;
    for (int task = tid; task < 536; task += 256) {   // 67 rows x 8 chunks of 8 channels
        int row = task >> 3, c8 = (task & 7) * 8;
        int t = t0 - 3 + row;
        if (t >= bstart) {
            i32x4 v = *(const i32x4*)(xiR + (size_t)t * D_INNER + d0 + c8);
            const unsigned short* vs = (const unsigned short*)&v;
#pragma unroll
            for (int i = 0; i < 8; ++i)
                xs[row * 65 + c8 + i] = __builtin_bit_cast(unsigned int, b2f(vs[i]));
        } else {
#pragma unroll
            for (int i = 0; i < 8; ++i) xs[row * 65 + c8 + i] = 0u;
        }
    }
    __syncthreads();
    {
        const int dl = tid & 63, tr = tid >> 6;
        const int d = d0 + dl, lt0 = tr * 16;
        const float w0 = cw[d * 4 + 0], w1 = cw[d * 4 + 1], w2 = cw[d * 4 + 2], w3 = cw[d * 4 + 3];
        const float bias = cb[d];
        float x0 = __builtin_bit_cast(float, xs[(lt0 + 0) * 65 + dl]);
        float x1 = __builtin_bit_cast(float, xs[(lt0 + 1) * 65 + dl]);
        float x2 = __builtin_bit_cast(float, xs[(lt0 + 2) * 65 + dl]);
#pragma unroll
        for (int i = 0; i < 16; ++i) {
            float x3 = __builtin_bit_cast(float, xs[(lt0 + 3 + i) * 65 + dl]);
            float a = bias + w0 * x0 + w1 * x1 + w2 * x2 + w3 * x3;
            ob[(lt0 + i) * 65 + dl] = f2b(a / (1.f + __expf(-a)));
            x0 = x1; x1 = x2; x2 = x3;
        }
    }
    __syncthreads();
#pragma unroll
    for (int it = 0; it < 2; ++it) {
        int k = tid + it * 256;
        int t = k >> 3, d8 = (k & 7) * 8;
        unsigned short o[8];
#pragma unroll
        for (int j = 0; j < 8; ++j) o[j] = (unsigned short)ob[t * 65 + d8 + j];
        *(i32x4*)(u_row + (size_t)(t0 + t) * D_INNER + d0 + d8) = *(const i32x4*)o;
    }
}

// ---------------- bf16 MFMA GEMM with global_load_lds staging ----------------
// EPI 0: row-major f32 partial store (split-K via blockIdx.z plane offset)
// EPI 1: dt_proj: delta=softplus(acc+bias[col]); ddu[t][d]=pack(delta,delta*u); uD[t][d]=u*D
// EPI 3: in_proj: col<2048 -> xi_row [t][d]; col>=2048 -> z_row [t][d]  (both coalesced)
template <int EPI>
__global__ __launch_bounds__(256) void gemm_mfma(
    const unsigned short* __restrict__ A, const unsigned short* __restrict__ B,
    void* __restrict__ C, void* __restrict__ C2,
    int M, int N, int K, int lda, int ldb, int ldc,
    const float* __restrict__ bias, const float* __restrict__ res,
    const float* __restrict__ aux) {
    __shared__ unsigned short As[128 * 32];
    __shared__ unsigned short Bs[128 * 32];
    const int tid = threadIdx.x;
    const int m0 = blockIdx.y * 128, n0 = blockIdx.x * 128;
    const int lane = tid & 63, wave = tid >> 6;
    const int wr = (wave >> 1) * 64, wc = (wave & 1) * 64;
    const int fr = lane & 15, fk = (lane >> 4) * 8;
    const int kspan = K / gridDim.z;
    const int kb = blockIdx.z * kspan;
    const int srow = lane >> 2, sc8 = (lane & 3) * 8;
    f32x4 acc[4][4] = {};
    for (int k0 = kb; k0 < kb + kspan; k0 += 32) {
#pragma unroll
        for (int i = 0; i < 2; ++i) {
            int q = wave + 4 * i;
            int row = q * 16 + srow;
            gload16(A + (size_t)(m0 + row) * lda + k0 + sc8, (unsigned short*)As + q * 512);
            gload16(B + (size_t)(n0 + row) * ldb + k0 + sc8, (unsigned short*)Bs + q * 512);
        }
        __syncthreads();
        bf16x8 af[4], bfr[4];
#pragma unroll
        for (int i = 0; i < 4; ++i) af[i]  = *(const bf16x8*)&As[(wr + i * 16 + fr) * 32 + fk];
#pragma unroll
        for (int j = 0; j < 4; ++j) bfr[j] = *(const bf16x8*)&Bs[(wc + j * 16 + fr) * 32 + fk];
#pragma unroll
        for (int i = 0; i < 4; ++i)
#pragma unroll
            for (int j = 0; j < 4; ++j)
                acc[i][j] = __builtin_amdgcn_mfma_f32_16x16x32_bf16(af[i], bfr[j], acc[i][j], 0, 0, 0);
        __syncthreads();
    }
    const int er = (lane >> 4) * 4;
    if (EPI == 3) {
        unsigned short* xiR = (unsigned short*)C;
        unsigned short* zR  = (unsigned short*)C2;
#pragma unroll
        for (int i = 0; i < 4; ++i)
#pragma unroll
            for (int j = 0; j < 4; ++j) {
                int row0 = m0 + wr + i * 16 + er;
                int col = n0 + wc + j * 16 + fr;
                unsigned short* dst;
                int colm;
                if (col < D_INNER) { dst = xiR; colm = col; }
                else               { dst = zR;  colm = col - D_INNER; }
#pragma unroll
                for (int r = 0; r < 4; ++r)
                    dst[(size_t)(row0 + r) * D_INNER + colm] = f2b(acc[i][j][r]);
            }
    } else if (EPI == 1) {
        const unsigned short* uR = (const unsigned short*)res;   // u_row bf16 [t][d]
        unsigned int* dduP = (unsigned int*)C;
        unsigned short* uDP = (unsigned short*)C2;
#pragma unroll
        for (int i = 0; i < 4; ++i)
#pragma unroll
            for (int j = 0; j < 4; ++j) {
                int row0 = m0 + wr + i * 16 + er;
                int col = n0 + wc + j * 16 + fr;
                float bb = bias[col];
                float Dv = aux[col];
#pragma unroll
                for (int r = 0; r < 4; ++r) {
                    size_t idx = (size_t)(row0 + r) * D_INNER + col;
                    float t = acc[i][j][r] + bb;
                    float v = fmaxf(t, 0.f) + __logf(1.f + __expf(-fabsf(t)));   // fast softplus
                    float uf = b2f(uR[idx]);
                    dduP[idx] = ((unsigned)f2b(v)) | (((unsigned)f2b(v * uf)) << 16);
                    uDP[idx] = f2b(uf * Dv);
                }
            }
    } else {
        float* Cs = (float*)C + (size_t)blockIdx.z * M * ldc;
#pragma unroll
        for (int i = 0; i < 4; ++i)
#pragma unroll
            for (int j = 0; j < 4; ++j) {
                int col = n0 + wc + j * 16 + fr;
                if (col < N) {
#pragma unroll
                    for (int r = 0; r < 4; ++r) {
                        int row = m0 + wr + i * 16 + er + r;
                        Cs[(size_t)row * ldc + col] = acc[i][j][r];
                    }
                }
            }
    }
}

// ---------------- out_proj split-K=4 combine + residual ----------------
__global__ void combine_residual(const float* __restrict__ part, const float* __restrict__ x,
                                 float* __restrict__ out) {
    int i = blockIdx.x * 256 + threadIdx.x;
    f32x4 s = *(const f32x4*)(x + (size_t)i * 4);
#pragma unroll
    for (int z = 0; z < 4; ++z)
        s += *(const f32x4*)(part + (size_t)z * NTOK * DIMX + (size_t)i * 4);
    *(f32x4*)(out + (size_t)i * 4) = s;
}

// ---------------- x_proj split-K combine ----------------
__global__ void xproj_combine(const float* __restrict__ xp, unsigned short* __restrict__ xdbl_b,
                              float* __restrict__ B_T, float* __restrict__ C_T) {
    int row = blockIdx.x;
    int col = threadIdx.x;
    if (col >= 96) return;
    float s = 0.f;
#pragma unroll
    for (int p = 0; p < 8; ++p) s += xp[(size_t)p * NTOK * 96 + (size_t)row * 96 + col];
    if (col < 64) xdbl_b[row * 64 + col] = f2b(s);
    else if (col < 80) B_T[(size_t)(col - 64) * NTOK + row] = s;
    else C_T[(size_t)(col - 80) * NTOK + row] = s;
}

// ================= Chunked selective scan: lane = channel, states in registers =================

__global__ __launch_bounds__(256) void scan_pass1(
    const unsigned int* __restrict__ ddu, const float* __restrict__ B_T,
    const float* __restrict__ A_log, float* __restrict__ hl, float* __restrict__ Pc) {
    __shared__ float bs[LC][20];
    const int tid = threadIdx.x;
    const int chunk = blockIdx.x;
    const int gchan = blockIdx.y * 256 + tid;
    const int b = gchan >> 11, d = gchan & (D_INNER - 1);
    const int tb = b * L_SEQ + chunk * LC;
    for (int v = tid; v < LC * 16; v += 256) {
        int t = v & (LC - 1), s = v >> 5;
        bs[t][s] = B_T[(size_t)s * NTOK + tb + t];
    }
    __syncthreads();
    float A2[D_STATE], h[D_STATE];
    const float* al = A_log + d * D_STATE;
#pragma unroll
    for (int s = 0; s < D_STATE; ++s) { A2[s] = -__expf(al[s]) * LOG2E; h[s] = 0.f; }
    float dsum = 0.f;
    const unsigned int* pd = ddu + (size_t)tb * D_INNER + d;
    unsigned int pf[8];
#pragma unroll
    for (int t = 0; t < 8; ++t) pf[t] = pd[(size_t)t * D_INNER];
#pragma unroll
    for (int t = 0; t < LC; ++t) {
        unsigned int v = pf[t & 7];
        if (t + 8 < LC) pf[t & 7] = pd[(size_t)(t + 8) * D_INNER];
        float dl = lo2f(v), du = hi2f(v);
        dsum += dl;
#pragma unroll
        for (int i = 0; i < 4; ++i) {
            f32x4 bv = *(const f32x4*)&bs[t][4 * i];
#pragma unroll
            for (int q = 0; q < 4; ++q) {
                int s = 4 * i + q;
                float e = exp2f(dl * A2[s]);
                h[s] = e * h[s] + du * bv[q];
            }
        }
    }
    float* ph = hl + (size_t)chunk * NLANE + (size_t)gchan * D_STATE;
    float* pp = Pc + (size_t)chunk * NLANE + (size_t)gchan * D_STATE;
#pragma unroll
    for (int q = 0; q < 4; ++q) {
        f32x4 hv = {h[4 * q], h[4 * q + 1], h[4 * q + 2], h[4 * q + 3]};
        f32x4 pv = {exp2f(dsum * A2[4 * q]),     exp2f(dsum * A2[4 * q + 1]),
                    exp2f(dsum * A2[4 * q + 2]), exp2f(dsum * A2[4 * q + 3])};
        *(f32x4*)(ph + 4 * q) = hv;
        *(f32x4*)(pp + 4 * q) = pv;
    }
}

__global__ __launch_bounds__(256) void scan_pass2(const float* __restrict__ hl,
                                                  const float* __restrict__ Pc,
                                                  float* __restrict__ hi) {
    int gid = blockIdx.x * 256 + threadIdx.x;
    float h = 0.f;
    hi[gid] = 0.f;
#pragma unroll
    for (int c = 1; c < NC; ++c) {
        h = hl[(size_t)(c - 1) * NLANE + gid] + Pc[(size_t)(c - 1) * NLANE + gid] * h;
        hi[(size_t)c * NLANE + gid] = h;
    }
}

__global__ __launch_bounds__(256) void scan_pass3(
    const unsigned int* __restrict__ ddu, const float* __restrict__ B_T,
    const float* __restrict__ C_T, const unsigned short* __restrict__ uD,
    const unsigned short* __restrict__ z_row, const float* __restrict__ A_log,
    const float* __restrict__ hi, unsigned short* __restrict__ y_row) {
    __shared__ float bcs[LC][36];
    const int tid = threadIdx.x;
    const int chunk = blockIdx.x;
    const int gchan = blockIdx.y * 256 + tid;
    const int b = gchan >> 11, d = gchan & (D_INNER - 1);
    const int tb = b * L_SEQ + chunk * LC;
    for (int v = tid; v < LC * 32; v += 256) {
        int t = v & (LC - 1), q = v >> 5;
        bcs[t][q] = (q < 16) ? B_T[(size_t)q * NTOK + tb + t]
                             : C_T[(size_t)(q - 16) * NTOK + tb + t];
    }
    __syncthreads();
    float A2[D_STATE], h[D_STATE];
    const float* al = A_log + d * D_STATE;
#pragma unroll
    for (int s = 0; s < D_STATE; ++s) A2[s] = -__expf(al[s]) * LOG2E;
    const float* ph = hi + (size_t)chunk * NLANE + (size_t)gchan * D_STATE;
#pragma unroll
    for (int q = 0; q < 4; ++q) {
        f32x4 hv = *(const f32x4*)(ph + 4 * q);
#pragma unroll
        for (int r = 0; r < 4; ++r) h[4 * q + r] = hv[r];
    }
    const unsigned int* pd = ddu + (size_t)tb * D_INNER + d;
    const unsigned short* pu = uD + (size_t)tb * D_INNER + d;
    const unsigned short* pz = z_row + (size_t)tb * D_INNER + d;
    unsigned short* py = y_row + (size_t)tb * D_INNER + d;
    unsigned int pf[4];
    unsigned short pfu[4], pfz[4];
#pragma unroll
    for (int t = 0; t < 4; ++t) {
        pf[t] = pd[(size_t)t * D_INNER];
        pfu[t] = pu[(size_t)t * D_INNER];
        pfz[t] = pz[(size_t)t * D_INNER];
    }
#pragma unroll
    for (int t = 0; t < LC; ++t) {
        unsigned int v = pf[t & 3];
        float uDv = b2f(pfu[t & 3]);
        float zz = b2f(pfz[t & 3]);
        if (t + 4 < LC) {
            pf[t & 3] = pd[(size_t)(t + 4) * D_INNER];
            pfu[t & 3] = pu[(size_t)(t + 4) * D_INNER];
            pfz[t & 3] = pz[(size_t)(t + 4) * D_INNER];
        }
        float dl = lo2f(v), du = hi2f(v);
        float y0 = 0.f, y1 = 0.f, y2 = 0.f, y3 = 0.f;
#pragma unroll
        for (int i = 0; i < 4; ++i) {
            f32x4 bv = *(const f32x4*)&bcs[t][4 * i];
            f32x4 cv = *(const f32x4*)&bcs[t][16 + 4 * i];
#pragma unroll
            for (int q = 0; q < 4; ++q) {
                int s = 4 * i + q;
                float e = exp2f(dl * A2[s]);
                h[s] = e * h[s] + du * bv[q];
                float yv = h[s] * cv[q];
                if (q == 0) y0 += yv;
                else if (q == 1) y1 += yv;
                else if (q == 2) y2 += yv;
                else y3 += yv;
            }
        }
        float y = (y0 + y1) + (y2 + y3);
        float yy = y + uDv;
        py[(size_t)t * D_INNER] = f2b(yy * (zz / (1.f + __expf(-zz))));
    }
}

extern "C" void kernel_launch(void* const* d_in, const int* in_sizes, int n_in,
                              void* d_out, int out_size, void* d_ws, size_t ws_size,
                              hipStream_t stream) {
    const float* x          = (const float*)d_in[0];
    const float* norm_w     = (const float*)d_in[1];
    const float* in_proj_w  = (const float*)d_in[2];
    const float* conv_w     = (const float*)d_in[3];
    const float* conv_b     = (const float*)d_in[4];
    const float* x_proj_w   = (const float*)d_in[5];
    const float* dt_proj_w  = (const float*)d_in[6];
    const float* dt_proj_b  = (const float*)d_in[7];
    const float* A_log      = (const float*)d_in[8];
    const float* D_param    = (const float*)d_in[9];
    const float* out_proj_w = (const float*)d_in[10];
    float* out = (float*)d_out;

    char* p = (char*)d_ws;
    unsigned short* xi_row = (unsigned short*)p; p += (size_t)NTOK * D_INNER * 2;  // 8.39 MB
    unsigned short* z_row  = (unsigned short*)p; p += (size_t)NTOK * D_INNER * 2;  // 8.39 MB
    unsigned int*   ddu    = (unsigned int*)p;   p += (size_t)NTOK * D_INNER * 4;  // 16.78 MB
    unsigned short* u_row  = (unsigned short*)p; p += (size_t)NTOK * D_INNER * 2;  // 8.39 MB
    unsigned short* uD     = (unsigned short*)p; p += (size_t)NTOK * D_INNER * 2;  // 8.39 MB
    unsigned short* y_row  = (unsigned short*)p; p += (size_t)NTOK * D_INNER * 2;  // 8.39 MB
    unsigned short* xdbl_b = (unsigned short*)p; p += (size_t)NTOK * 64 * 2;       // 0.26 MB
    float* B_T = (float*)p;  p += (size_t)D_STATE * NTOK * 4;                      // 0.13 MB
    float* C_T = (float*)p;  p += (size_t)D_STATE * NTOK * 4;                      // 0.13 MB
    unsigned short* xn_b = (unsigned short*)p; p += (size_t)NTOK * DIMX * 2;       // 4.19 MB
    unsigned short* w_in_b  = (unsigned short*)p; p += (size_t)2 * D_INNER * DIMX * 2;  // 8.39 MB
    unsigned short* w_x_b   = (unsigned short*)p; p += (size_t)96 * D_INNER * 2;
    unsigned short* w_dt_b  = (unsigned short*)p; p += (size_t)D_INNER * DT_RANK * 2;
    unsigned short* w_out_b = (unsigned short*)p; p += (size_t)DIMX * D_INNER * 2;

    // overlays (disjoint lifetimes):
    float* xp_part = (float*)y_row;            // 6.29 MB (y_row written only by pass3)
    float* hl = (float*)u_row;                 // 8.39 MB (u_row dead after dt_proj; pass1+)
    float* Pc = (float*)w_in_b;                // 8.39 MB (w_in dead after in_proj; pass1+)
    float* hi = (float*)xi_row;                // 8.39 MB (xi_row dead after conv; pass2+)
    float* out_part = (float*)ddu;             // 33.56 MB = ddu(16.78)+u_row/hl(8.39)+uD(8.39),
                                               // contiguous, all dead after pass3 (4 K-planes)

    // 0. fused prep: weight conversions + RMSNorm
    prep_kernel<<<NWCONV + NTOK, 256, 0, stream>>>(
        in_proj_w, x_proj_w, dt_proj_w, out_proj_w, x, norm_w,
        w_in_b, w_x_b, w_dt_b, w_out_b, xn_b);
    // 1. in_proj: xi_row [t][d] + z_row [t][d]
    gemm_mfma<3><<<dim3(32, 16), 256, 0, stream>>>(xn_b, w_in_b, xi_row, z_row,
        NTOK, 2 * D_INNER, DIMX, DIMX, DIMX, D_INNER, nullptr, nullptr, nullptr);
    // 2. FUSED conv + SiLU -> u_row [t][d]
    conv_silu_row<<<dim3(NTOK / 64, D_INNER / 64), 256, 0, stream>>>(
        xi_row, conv_w, conv_b, u_row);
    // 3. x_proj split-K=8 partials + combine
    gemm_mfma<0><<<dim3(1, 16, 8), 256, 0, stream>>>(u_row, w_x_b, xp_part, nullptr,
        NTOK, 96, D_INNER, D_INNER, D_INNER, 96, nullptr, nullptr, nullptr);
    xproj_combine<<<NTOK, 128, 0, stream>>>(xp_part, xdbl_b, B_T, C_T);
    // 4. dt_proj: ddu [t][d] (packed bf16 delta,du) + uD [t][d] (u*D)
    gemm_mfma<1><<<dim3(16, 16), 256, 0, stream>>>(xdbl_b, w_dt_b, ddu, uD,
        NTOK, D_INNER, DT_RANK, 64, DT_RANK, D_INNER, dt_proj_b, (const float*)u_row, D_param);
    // 5. chunked selective scan (lane=channel, states in registers)
    scan_pass1<<<dim3(NC, NCH / 256), 256, 0, stream>>>(ddu, B_T, A_log, hl, Pc);
    scan_pass2<<<NLANE / 256, 256, 0, stream>>>(hl, Pc, hi);
    scan_pass3<<<dim3(NC, NCH / 256), 256, 0, stream>>>(ddu, B_T, C_T, uD, z_row, A_log, hi, y_row);
    // 6. out_proj split-K=4 -> partials (2 blocks/CU; ddu region dead after pass3)
    gemm_mfma<0><<<dim3(8, 16, 4), 256, 0, stream>>>(y_row, w_out_b, out_part, nullptr,
        NTOK, DIMX, D_INNER, D_INNER, D_INNER, DIMX, nullptr, nullptr, nullptr);
    // 7. combine partials + residual -> out
    combine_residual<<<NTOK * DIMX / 4 / 256, 256, 0, stream>>>(out_part, x, out);
}